// Round 1
// baseline (846.270 us; speedup 1.0000x reference)
//
#include <hip/hip_runtime.h>

// Axial attention for N=16, C=64, H=W=256.
// K1: h (NCHW f32) -> hT (N,H,W,C) bf16            [ws 0..128MB)
// K2: row attention (per (n,w), attend over H) -> attnOut (N,H,W,C) bf16 [ws 128..256MB)
// K3: col attention (per (n,y), attend over W) + attnOut + h -> out (NCHW f32)
//
// Scores use the identity softmax(q.k^T) == softmax( (X*At*X^T + w[g]) / 16 ),
// At = Wq^T Wk, w[g] = X[g].(Wk^T bq); query-side bias terms are row-constant and cancel.
// V bias added in epilogue (softmax rows sum to 1).

typedef unsigned short u16t;
typedef __bf16 bf16x8 __attribute__((ext_vector_type(8)));
typedef float  f32x4  __attribute__((ext_vector_type(4)));
typedef u16t   us8    __attribute__((ext_vector_type(8)));
typedef u16t   us4    __attribute__((ext_vector_type(4)));

#define DEVINL __device__ __forceinline__

DEVINL u16t f2bf(float f){
    unsigned u = __builtin_bit_cast(unsigned, f);
    u += 0x7fffu + ((u >> 16) & 1u);          // round-to-nearest-even
    return (u16t)(u >> 16);
}
DEVINL float bf2f(u16t h){
    unsigned u = ((unsigned)h) << 16;
    return __builtin_bit_cast(float, u);
}
DEVINL f32x4 mfma16(bf16x8 a, bf16x8 b, f32x4 c){
    return __builtin_amdgcn_mfma_f32_16x16x32_bf16(a, b, c, 0, 0, 0);
}
// LDS tiles: row-major, XOR swizzle byte ^= ((row&7)<<4) to break bank conflicts,
// preserves 16B alignment so ds_read_b128 works.
DEVINL bf16x8 lds_frag(const u16t* base, int row, int kchunk, int rowStrideB){
    const char* p = (const char*)base + row * rowStrideB + (((kchunk) << 4) ^ ((row & 7) << 4));
    return *(const bf16x8*)p;
}
DEVINL void lds_w16(u16t* base, int row, int col, int rowStrideB, u16t v){
    char* p = (char*)base + row * rowStrideB + ((col * 2) ^ ((row & 7) << 4));
    *(u16t*)p = v;
}
DEVINL void lds_w128(u16t* base, int row, int cchunk, int rowStrideB, us8 v){
    char* p = (char*)base + row * rowStrideB + (((cchunk) << 4) ^ ((row & 7) << 4));
    *(us8*)p = v;
}

// ---------------- K1: transpose h (N,C,H,W) f32 -> hT (N,H,W,C) bf16 ----------------
__global__ __launch_bounds__(256) void transpose_kernel(const float* __restrict__ h,
                                                        u16t* __restrict__ hT){
    __shared__ float tile[64][257];
    const int bid = blockIdx.x;          // n*256 + y
    const int n = bid >> 8, y = bid & 255;
    const int tid = threadIdx.x;
    {
        const int c = tid >> 2, w0 = (tid & 3) * 64;
        const int base = ((n * 64 + c) * 256 + y) * 256 + w0;
        #pragma unroll
        for (int i = 0; i < 16; ++i){
            f32x4 v = *(const f32x4*)(h + base + i * 4);
            tile[c][w0 + i*4 + 0] = v[0];
            tile[c][w0 + i*4 + 1] = v[1];
            tile[c][w0 + i*4 + 2] = v[2];
            tile[c][w0 + i*4 + 3] = v[3];
        }
    }
    __syncthreads();
    #pragma unroll
    for (int j = 0; j < 4; ++j){
        const int task = tid + 256 * j;
        const int w = task >> 2, c0 = (task & 3) * 16;
        us8 o0, o1;
        #pragma unroll
        for (int e = 0; e < 8; ++e) o0[e] = f2bf(tile[c0 + e][w]);
        #pragma unroll
        for (int e = 0; e < 8; ++e) o1[e] = f2bf(tile[c0 + 8 + e][w]);
        const int ob = ((n * 256 + y) * 256 + w) * 64 + c0;
        *(us8*)(hT + ob)     = o0;
        *(us8*)(hT + ob + 8) = o1;
    }
}

// ---------------- K2/K3: attention. COL=0: row attn -> attnOut. COL=1: col attn + combine -> out.
template<int COL>
__global__ __launch_bounds__(512) void attn_kernel(
    const u16t* __restrict__ hT,
    const float* __restrict__ wq, const float* __restrict__ bq,
    const float* __restrict__ wk, const float* __restrict__ wvw,
    const float* __restrict__ bvp,
    u16t* __restrict__ attnOut,
    const float* __restrict__ hsrc, float* __restrict__ outp)
{
    __shared__ __align__(16) u16t Xs[16384];   // X tile 256x64 bf16 (swizzled rows of 128B)
    __shared__ __align__(16) u16t Vt[16384];   // V^T 64x256 bf16 (swizzled rows of 512B)
    __shared__ __align__(16) u16t Sc[32768];   // per-wave 8KB scratch (q~ stage + P); later OutS
    __shared__ __align__(16) u16t AtF[4096];   // At = Wq^T Wk in B-frag layout
    __shared__ float w16s[256];
    __shared__ float wkbqs[64];
    __shared__ float bvs[64];

    const int tid  = threadIdx.x;
    const int lane = tid & 63;
    const int wv   = tid >> 6;
    const int bid  = blockIdx.x;
    const int n    = bid >> 8;
    const int idx  = bid & 255;               // w (row mode) or y (col mode)
    const int l15  = lane & 15;
    const int l4   = lane >> 4;
    const int nbase = n * 4194304;            // n*H*W*C

    // phase 0a: stage X into LDS
    #pragma unroll
    for (int pass = 0; pass < 4; ++pass){
        const int i = pass * 512 + tid;
        const int row = i >> 3, cc = i & 7;
        const int goff = COL ? (nbase + idx * 16384 + row * 64 + cc * 8)
                             : (nbase + row * 16384 + idx * 64 + cc * 8);
        us8 v = *(const us8*)(hT + goff);
        lds_w128(Xs, row, cc, 128, v);
    }

    // phase 0b: compute At = Wq^T Wk via MFMA (consistent frag maps both sides),
    // scatter C/D into AtF in B-frag layout.
    {
        const int mtA = wv >> 1;
        us8 aqu[2];
        #pragma unroll
        for (int kt = 0; kt < 2; ++kt)
            #pragma unroll
            for (int e = 0; e < 8; ++e)
                aqu[kt][e] = f2bf(wq[(kt*32 + l4*8 + e)*64 + mtA*16 + l15]);
        #pragma unroll
        for (int t2 = 0; t2 < 2; ++t2){
            const int ntA = (2*wv + t2) & 3;
            us8 bku[2];
            #pragma unroll
            for (int kt = 0; kt < 2; ++kt)
                #pragma unroll
                for (int e = 0; e < 8; ++e)
                    bku[kt][e] = f2bf(wk[(kt*32 + l4*8 + e)*64 + ntA*16 + l15]);
            f32x4 acc = {0.f,0.f,0.f,0.f};
            acc = mfma16(__builtin_bit_cast(bf16x8, aqu[0]), __builtin_bit_cast(bf16x8, bku[0]), acc);
            acc = mfma16(__builtin_bit_cast(bf16x8, aqu[1]), __builtin_bit_cast(bf16x8, bku[1]), acc);
            #pragma unroll
            for (int r = 0; r < 4; ++r){
                const int a = mtA*16 + l4*4 + r;       // k-index of At as B operand
                const int kt2 = a >> 5, rem = a & 31;
                AtF[(((kt2*4 + ntA)*64) + (rem>>3)*16 + l15)*8 + (rem&7)] = f2bf(acc[r]);
            }
        }
    }
    if (tid < 64){
        float acc = 0.f;
        for (int o = 0; o < 64; ++o) acc += wk[o*64 + tid] * bq[o];
        wkbqs[tid] = acc;
        bvs[tid] = bvp[tid];
    }
    __syncthreads();

    // phase 1: V = X @ Wv^T (no bias) -> Vt (transposed, swizzled); w16s[g] = X[g].wkbq / 16
    {
        bf16x8 wvf[2][4];
        #pragma unroll
        for (int kt = 0; kt < 2; ++kt)
            #pragma unroll
            for (int nt = 0; nt < 4; ++nt){
                const int o = nt*16 + l15;
                const int cb = kt*32 + l4*8;
                f32x4 v0 = *(const f32x4*)(wvw + o*64 + cb);
                f32x4 v1 = *(const f32x4*)(wvw + o*64 + cb + 4);
                us8 u;
                #pragma unroll
                for (int e = 0; e < 4; ++e){ u[e] = f2bf(v0[e]); u[4+e] = f2bf(v1[e]); }
                wvf[kt][nt] = __builtin_bit_cast(bf16x8, u);
            }
        #pragma unroll
        for (int g2 = 0; g2 < 2; ++g2){
            const int gt = wv*2 + g2;
            bf16x8 a0 = lds_frag(Xs, gt*16 + l15, l4,     128);
            bf16x8 a1 = lds_frag(Xs, gt*16 + l15, 4 + l4, 128);
            #pragma unroll
            for (int nt = 0; nt < 4; ++nt){
                f32x4 acc = {0.f,0.f,0.f,0.f};
                acc = mfma16(a0, wvf[0][nt], acc);
                acc = mfma16(a1, wvf[1][nt], acc);
                const int c = nt*16 + l15;
                #pragma unroll
                for (int r = 0; r < 4; ++r)
                    lds_w16(Vt, c, gt*16 + l4*4 + r, 512, f2bf(acc[r]));
            }
        }
    }
    if (tid < 256){
        float acc = 0.f;
        #pragma unroll
        for (int cc = 0; cc < 8; ++cc){
            const char* p = (const char*)Xs + tid*128 + ((cc<<4) ^ ((tid&7)<<4));
            us8 xv = *(const us8*)p;
            #pragma unroll
            for (int e = 0; e < 8; ++e) acc += bf2f(xv[e]) * wkbqs[cc*8+e];
        }
        w16s[tid] = acc * 0.0625f;
    }
    __syncthreads();

    // phase 2: per-wave attention over 2 row-tiles of 16
    bf16x8 af[2][4];
    #pragma unroll
    for (int kt = 0; kt < 2; ++kt)
        #pragma unroll
        for (int nt = 0; nt < 4; ++nt)
            af[kt][nt] = *(const bf16x8*)(AtF + ((kt*4+nt)*64 + lane)*8);

    u16t* sc = Sc + wv * 4096;
    f32x4 outv[2][4];

    #pragma unroll
    for (int mi = 0; mi < 2; ++mi){
        const int mt = wv*2 + mi;
        // q~ = X @ At  (16x64), stage to scratch for A-frag reads
        {
            bf16x8 xa0 = lds_frag(Xs, mt*16 + l15, l4,     128);
            bf16x8 xa1 = lds_frag(Xs, mt*16 + l15, 4 + l4, 128);
            #pragma unroll
            for (int nt = 0; nt < 4; ++nt){
                f32x4 acc = {0.f,0.f,0.f,0.f};
                acc = mfma16(xa0, af[0][nt], acc);
                acc = mfma16(xa1, af[1][nt], acc);
                #pragma unroll
                for (int r = 0; r < 4; ++r)
                    lds_w16(sc, l4*4 + r, nt*16 + l15, 128, f2bf(acc[r]));
            }
        }
        bf16x8 qa0 = lds_frag(sc, l15, l4,     128);
        bf16x8 qa1 = lds_frag(sc, l15, 4 + l4, 128);
        // scores S = q~ @ X^T / 16 + w[g]
        f32x4 sv[16];
        #pragma unroll
        for (int nt = 0; nt < 16; ++nt){
            bf16x8 kb0 = lds_frag(Xs, nt*16 + l15, l4,     128);
            bf16x8 kb1 = lds_frag(Xs, nt*16 + l15, 4 + l4, 128);
            f32x4 acc = {0.f,0.f,0.f,0.f};
            acc = mfma16(qa0, kb0, acc);
            acc = mfma16(qa1, kb1, acc);
            const float wg = w16s[nt*16 + l15];
            #pragma unroll
            for (int r = 0; r < 4; ++r) sv[nt][r] = acc[r]*0.0625f + wg;
        }
        // softmax per row (row lives in the 16 lanes sharing l4; 16 cols per lane)
        float rcp[4];
        #pragma unroll
        for (int r = 0; r < 4; ++r){
            float mx = sv[0][r];
            #pragma unroll
            for (int nt = 1; nt < 16; ++nt) mx = fmaxf(mx, sv[nt][r]);
            mx = fmaxf(mx, __shfl_xor(mx, 1));
            mx = fmaxf(mx, __shfl_xor(mx, 2));
            mx = fmaxf(mx, __shfl_xor(mx, 4));
            mx = fmaxf(mx, __shfl_xor(mx, 8));
            float sum = 0.f;
            #pragma unroll
            for (int nt = 0; nt < 16; ++nt){
                float p = __expf(sv[nt][r] - mx);
                sv[nt][r] = p; sum += p;
            }
            sum += __shfl_xor(sum, 1);
            sum += __shfl_xor(sum, 2);
            sum += __shfl_xor(sum, 4);
            sum += __shfl_xor(sum, 8);
            rcp[r] = 1.f / sum;
        }
        // stage P (unnormalized) to scratch
        #pragma unroll
        for (int nt = 0; nt < 16; ++nt){
            const int g = nt*16 + l15;
            #pragma unroll
            for (int r = 0; r < 4; ++r)
                lds_w16(sc, l4*4 + r, g, 512, f2bf(sv[nt][r]));
        }
        // out = P @ V
        f32x4 po[4] = {{0.f,0.f,0.f,0.f},{0.f,0.f,0.f,0.f},{0.f,0.f,0.f,0.f},{0.f,0.f,0.f,0.f}};
        #pragma unroll
        for (int kt = 0; kt < 8; ++kt){
            bf16x8 pa = lds_frag(sc, l15, kt*4 + l4, 512);
            #pragma unroll
            for (int nt = 0; nt < 4; ++nt){
                bf16x8 vb = lds_frag(Vt, nt*16 + l15, kt*4 + l4, 512);
                po[nt] = mfma16(pa, vb, po[nt]);
            }
        }
        if (!COL){
            #pragma unroll
            for (int nt = 0; nt < 4; ++nt){
                const int c = nt*16 + l15;
                const float b = bvs[c];
                #pragma unroll
                for (int r = 0; r < 4; ++r){
                    const int y = mt*16 + l4*4 + r;
                    attnOut[nbase + y*16384 + idx*64 + c] = f2bf(po[nt][r]*rcp[r] + b);
                }
            }
        } else {
            #pragma unroll
            for (int nt = 0; nt < 4; ++nt){
                const int c = nt*16 + l15;
                const float b = bvs[c];
                #pragma unroll
                for (int r = 0; r < 4; ++r){
                    const int w = mt*16 + l4*4 + r;
                    const float ar = bf2f(attnOut[nbase + idx*16384 + w*64 + c]);
                    outv[mi][nt][r] = po[nt][r]*rcp[r] + b + ar;
                }
            }
        }
    }

    if (COL){
        __syncthreads();                      // all P reads done; reuse Sc as OutS [c][w]
        #pragma unroll
        for (int mi = 0; mi < 2; ++mi){
            const int mt = wv*2 + mi;
            #pragma unroll
            for (int nt = 0; nt < 4; ++nt){
                const int c = nt*16 + l15;
                #pragma unroll
                for (int r = 0; r < 4; ++r)
                    lds_w16(Sc, c, mt*16 + l4*4 + r, 512, f2bf(outv[mi][nt][r]));
            }
        }
        __syncthreads();
        // final: out[n][c][y][w] = OutS[c][w] + h ; coalesced 1KB row writes
        #pragma unroll
        for (int k = 0; k < 8; ++k){
            const int c = wv*8 + k;
            const char* p = (const char*)Sc + c*512 + ((lane*8) ^ ((c&7)<<4));
            us4 ov = *(const us4*)p;
            const int gb = ((n*64 + c)*256 + idx)*256 + lane*4;
            f32x4 hres = *(const f32x4*)(hsrc + gb);
            f32x4 res;
            #pragma unroll
            for (int e = 0; e < 4; ++e) res[e] = hres[e] + bf2f(ov[e]);
            *(f32x4*)(outp + gb) = res;
        }
    }
}

extern "C" void kernel_launch(void* const* d_in, const int* in_sizes, int n_in,
                              void* d_out, int out_size, void* d_ws, size_t ws_size,
                              hipStream_t stream){
    const float* h   = (const float*)d_in[0];
    const float* wq  = (const float*)d_in[1];
    const float* bq  = (const float*)d_in[2];
    const float* wk  = (const float*)d_in[3];
    // d_in[4] = bk: cancels in softmax (row-constant), unused.
    const float* wvw = (const float*)d_in[5];
    const float* bv  = (const float*)d_in[6];
    float* out = (float*)d_out;

    u16t* hT      = (u16t*)d_ws;          // 67,108,864 bf16 = 128MB
    u16t* attnOut = hT + 67108864;        // 67,108,864 bf16 = 128MB

    transpose_kernel<<<4096, 256, 0, stream>>>(h, hT);
    attn_kernel<0><<<4096, 512, 0, stream>>>(hT, wq, bq, wk, wvw, bv, attnOut, h, out);
    attn_kernel<1><<<4096, 512, 0, stream>>>(hT, wq, bq, wk, wvw, bv, attnOut, h, out);
}